// Round 11
// baseline (1325.073 us; speedup 1.0000x reference)
//
#include <hip/hip_runtime.h>
#include <cstdint>
#include <cstddef>

#define ALPHA 0.2f

__device__ __forceinline__ float lrelu(float x) { return x > 0.f ? x : ALPHA * x; }

// round-to-nearest-even bf16 quantization, kept in f32
__device__ __forceinline__ float qbf(float x)
{
    uint32_t u = __float_as_uint(x);
    uint32_t r = (u + 0x7FFFu + ((u >> 16) & 1u)) & 0xFFFF0000u;
    return __uint_as_float(r);
}

// bf16 bit helpers
__device__ __forceinline__ uint32_t bfbits(float x)
{
    uint32_t u = __float_as_uint(x);
    return (u + 0x7FFFu + ((u >> 16) & 1u)) >> 16;
}
__device__ __forceinline__ uint32_t pack2(float lo, float hi)
{
    return bfbits(lo) | (bfbits(hi) << 16);
}
__device__ __forceinline__ float bf2f(ushort u)
{
    return __uint_as_float(((uint32_t)u) << 16);
}

// ---------------------------------------------------------------------------
// GEMM1 + fused scores: H[n, h*64+o] = sum_k q(x[n,k]) * q(Wh[h,k,o]),
// s1src/s1dst from the f32 accumulators. H stored as bf16.
// Tile 64 rows x 256 cols, BK=32, 256 threads, micro 4x16.
// ---------------------------------------------------------------------------
__global__ __launch_bounds__(256) void k_gemm1(const float* __restrict__ x,
                                               const float* __restrict__ Wh,
                                               const float* __restrict__ a,
                                               ushort* __restrict__ Hb,
                                               float* __restrict__ s1src,
                                               float* __restrict__ s1dst, int n)
{
    __shared__ float As[32][68];    // transposed A tile, padded
    __shared__ float Bs[32][256];
    __shared__ float Pa[64][17];    // per-(row,txgroup) partial dots (src)
    __shared__ float Pb[64][17];    // (dst)
    __shared__ float avs[256], avd[256];
    const int tid = threadIdx.x;
    const int row0 = blockIdx.x * 64;
    const int tx = tid & 15, ty = tid >> 4;

    {
        int h = tid >> 6, o = tid & 63;
        avs[tid] = qbf(a[h * 128 + o]);
        avd[tid] = qbf(a[h * 128 + 64 + o]);
    }

    float acc[4][16];
#pragma unroll
    for (int r = 0; r < 4; ++r)
#pragma unroll
        for (int c = 0; c < 16; ++c) acc[r][c] = 0.f;

    for (int k0 = 0; k0 < 256; k0 += 32) {
        for (int j = tid; j < 512; j += 256) {
            int r = j >> 3, kk = (j & 7) << 2;
            int gr = row0 + r; if (gr >= n) gr = n - 1;
            const float4 v = *(const float4*)&x[(size_t)gr * 256 + k0 + kk];
            As[kk + 0][r] = qbf(v.x); As[kk + 1][r] = qbf(v.y);
            As[kk + 2][r] = qbf(v.z); As[kk + 3][r] = qbf(v.w);
        }
        for (int j = tid; j < 2048; j += 256) {
            int kk = j >> 6, c4 = j & 63;
            int h = c4 >> 4, o = (c4 & 15) << 2;
            const float4 v = *(const float4*)&Wh[h * 16384 + (k0 + kk) * 64 + o];
            float* bp = &Bs[kk][c4 << 2];
            bp[0] = qbf(v.x); bp[1] = qbf(v.y); bp[2] = qbf(v.z); bp[3] = qbf(v.w);
        }
        __syncthreads();
#pragma unroll
        for (int kk = 0; kk < 32; ++kk) {
            const float4 av4 = *(const float4*)&As[kk][ty << 2];
            const float4 b0 = *(const float4*)&Bs[kk][tx * 16 + 0];
            const float4 b1 = *(const float4*)&Bs[kk][tx * 16 + 4];
            const float4 b2 = *(const float4*)&Bs[kk][tx * 16 + 8];
            const float4 b3 = *(const float4*)&Bs[kk][tx * 16 + 12];
            const float av[4]  = {av4.x, av4.y, av4.z, av4.w};
            const float bv[16] = {b0.x, b0.y, b0.z, b0.w, b1.x, b1.y, b1.z, b1.w,
                                  b2.x, b2.y, b2.z, b2.w, b3.x, b3.y, b3.z, b3.w};
#pragma unroll
            for (int r = 0; r < 4; ++r)
#pragma unroll
                for (int c = 0; c < 16; ++c) acc[r][c] += av[r] * bv[c];
        }
        __syncthreads();
    }
    // store H (bf16) + stash score partials (f32)
#pragma unroll
    for (int r = 0; r < 4; ++r) {
        int row = (ty << 2) + r;
        int gr = row0 + row;
        float ps = 0.f, pd = 0.f;
#pragma unroll
        for (int c = 0; c < 16; ++c) {
            ps += acc[r][c] * avs[tx * 16 + c];
            pd += acc[r][c] * avd[tx * 16 + c];
        }
        Pa[row][tx] = ps;
        Pb[row][tx] = pd;
        if (gr < n) {
            uint32_t* dst = (uint32_t*)&Hb[(size_t)gr * 256 + tx * 16];
            uint4 u0, u1;
            u0.x = pack2(acc[r][0],  acc[r][1]);  u0.y = pack2(acc[r][2],  acc[r][3]);
            u0.z = pack2(acc[r][4],  acc[r][5]);  u0.w = pack2(acc[r][6],  acc[r][7]);
            u1.x = pack2(acc[r][8],  acc[r][9]);  u1.y = pack2(acc[r][10], acc[r][11]);
            u1.z = pack2(acc[r][12], acc[r][13]); u1.w = pack2(acc[r][14], acc[r][15]);
            *(uint4*)&dst[0] = u0;
            *(uint4*)&dst[4] = u1;
        }
    }
    __syncthreads();
    for (int o = tid; o < 512; o += 256) {
        int row = o >> 3, h = (o >> 1) & 3, which = o & 1;
        const float* P = which ? &Pb[row][0] : &Pa[row][0];
        float s = P[h * 4 + 0] + P[h * 4 + 1] + P[h * 4 + 2] + P[h * 4 + 3];
        int gr = row0 + row;
        if (gr < n) {
            if (which) s1dst[gr * 4 + h] = s;
            else       s1src[gr * 4 + h] = s;
        }
    }
}

// ---------------------------------------------------------------------------
// CSR build (scatter stores EDGE IDs; buckets sorted by edge id)
// ---------------------------------------------------------------------------
__global__ void k_zero(int* __restrict__ p, int n)
{
    int i = blockIdx.x * 256 + threadIdx.x;
    if (i < n) p[i] = 0;
}

__global__ void k_hist(const int* __restrict__ src, int* __restrict__ counts, int e)
{
    int i = blockIdx.x * 256 + threadIdx.x;
    if (i < e) atomicAdd(&counts[src[i]], 1);
}

__global__ __launch_bounds__(256) void k_blocksum(const int* __restrict__ counts,
                                                  int* __restrict__ bsum, int n)
{
    int tid = threadIdx.x;
    int i0 = blockIdx.x * 2048 + tid * 8;
    int s = 0;
#pragma unroll
    for (int k = 0; k < 8; ++k) {
        int i = i0 + k;
        if (i < n) s += counts[i];
    }
#pragma unroll
    for (int m = 32; m >= 1; m >>= 1) s += __shfl_xor(s, m);
    __shared__ int ws[4];
    int lane = tid & 63, wv = tid >> 6;
    if (lane == 0) ws[wv] = s;
    __syncthreads();
    if (tid == 0) bsum[blockIdx.x] = ws[0] + ws[1] + ws[2] + ws[3];
}

__global__ void k_scanmeta(const int* __restrict__ bsum, int* __restrict__ choff, int nchunk)
{
    int lane = threadIdx.x;   // 64 threads, nchunk <= 64
    int v = (lane < nchunk) ? bsum[lane] : 0;
    int incl = v;
#pragma unroll
    for (int d = 1; d < 64; d <<= 1) {
        int t = __shfl_up(incl, d);
        if (lane >= d) incl += t;
    }
    if (lane < nchunk) choff[lane] = incl - v;
}

__global__ __launch_bounds__(256) void k_apply(const int* __restrict__ counts,
                                               const int* __restrict__ choff,
                                               int* __restrict__ offsets,
                                               int* __restrict__ cursor, int n)
{
    int tid = threadIdx.x;
    int i0 = blockIdx.x * 2048 + tid * 8;
    int c[8]; int s = 0;
#pragma unroll
    for (int k = 0; k < 8; ++k) {
        int i = i0 + k;
        c[k] = (i < n) ? counts[i] : 0;
        s += c[k];
    }
    int lane = tid & 63, wv = tid >> 6;
    int incl = s;
#pragma unroll
    for (int d = 1; d < 64; d <<= 1) {
        int t = __shfl_up(incl, d);
        if (lane >= d) incl += t;
    }
    __shared__ int ws[4];
    if (lane == 63) ws[wv] = incl;
    __syncthreads();
    int woff = 0;
    for (int w = 0; w < 4; ++w)
        if (w < wv) woff += ws[w];
    int run = incl - s + woff + choff[blockIdx.x];
#pragma unroll
    for (int k = 0; k < 8; ++k) {
        int i = i0 + k;
        if (i < n) { offsets[i] = run; cursor[i] = run; }
        run += c[k];
        if (i == n - 1) offsets[n] = run;
    }
}

__global__ void k_scatter(const int* __restrict__ src,
                          int* __restrict__ cursor, int* __restrict__ csr, int e)
{
    int i = blockIdx.x * 256 + threadIdx.x;
    if (i < e) {
        int pos = atomicAdd(&cursor[src[i]], 1);
        csr[pos] = i;                    // edge id (unique key)
    }
}

// sort each bucket's edge ids ascending (deterministic order == np order)
__global__ __launch_bounds__(256) void k_sortcsr(const int* __restrict__ offsets,
                                                 int* __restrict__ csr, int n)
{
    int gtid = blockIdx.x * 256 + threadIdx.x;
    int node = gtid >> 6, lane = gtid & 63;
    if (node >= n) return;
    int beg = offsets[node], end = offsets[node + 1];
    int cnt = end - beg;
    if (cnt <= 0) return;
    if (cnt <= 64) {
        int v = (lane < cnt) ? csr[beg + lane] : 0x7FFFFFFF;
#pragma unroll
        for (int k = 2; k <= 64; k <<= 1) {
#pragma unroll
            for (int j = k >> 1; j > 0; j >>= 1) {
                int o = __shfl_xor(v, j);
                bool up    = ((lane & k) == 0);
                bool lower = ((lane & j) == 0);
                int mn = min(v, o), mx = max(v, o);
                v = (lower == up) ? mn : mx;
            }
        }
        if (lane < cnt) csr[beg + lane] = v;
    } else {
        if (lane == 0) {    // cold path: degree > 64
            for (int i = beg + 1; i < end; ++i) {
                int key = csr[i]; int j = i - 1;
                while (j >= beg && csr[j] > key) { csr[j + 1] = csr[j]; --j; }
                csr[j + 1] = key;
            }
        }
    }
}

// ---------------------------------------------------------------------------
// w1 + csrd: slot-parallel layer-1 edge weights (4 heads) from sorted eids
// ---------------------------------------------------------------------------
__global__ void k_w1(const int* __restrict__ csr_eid,
                     const int* __restrict__ src, const int* __restrict__ dst,
                     const float* __restrict__ s1src, const float* __restrict__ s1dst,
                     int* __restrict__ csrd, float* __restrict__ w1, int e)
{
    int i = blockIdx.x * 256 + threadIdx.x;
    if (i >= e) return;
    int eid = csr_eid[i];
    int s = src[eid], d = dst[eid];
    csrd[i] = d;
    const float4 aa = *(const float4*)&s1src[(size_t)s * 4];
    const float4 bb = *(const float4*)&s1dst[(size_t)d * 4];
    float4 w;
    w.x = expf(-lrelu(aa.x + bb.x));
    w.y = expf(-lrelu(aa.y + bb.y));
    w.z = expf(-lrelu(aa.z + bb.z));
    w.w = expf(-lrelu(aa.w + bb.w));
    *(float4*)&w1[(size_t)i * 4] = w;
}

// layer-2 edge weights (after agg1 produces s2)
__global__ void k_w2(const int* __restrict__ csr_eid,
                     const int* __restrict__ src, const int* __restrict__ dst,
                     const float* __restrict__ s2src, const float* __restrict__ s2dst,
                     float* __restrict__ w2, int e)
{
    int i = blockIdx.x * 256 + threadIdx.x;
    if (i >= e) return;
    int eid = csr_eid[i];
    float z = s2src[src[eid]] + s2dst[dst[eid]];
    w2[i] = expf(-lrelu(z));
}

// ---------------------------------------------------------------------------
// agg1 (fused with GEMM2): per-node wave; bf16 H gather; 4-deep pipelined.
// readlane indices here are wave-uniform loop constants (legal).
// Invalid pipeline slots carry weight 0 and gather row 0 (always cached).
// ---------------------------------------------------------------------------
__global__ __launch_bounds__(256) void k_agg1(const int* __restrict__ csrd,
                                              const int* __restrict__ offsets,
                                              const ushort* __restrict__ Hb,
                                              const float* __restrict__ w1,
                                              const float* __restrict__ Wout,
                                              const float* __restrict__ aout,
                                              float* __restrict__ h2,
                                              float* __restrict__ s2src,
                                              float* __restrict__ s2dst, int n)
{
    __shared__ float Wt[32][256];   // Wt[c][k] = q(Wout[k,c])
    const int tid = threadIdx.x;
    for (int j = tid; j < 8192; j += 256) {   // conflict-free writes (k contiguous)
        int c = j >> 8, k = j & 255;
        Wt[c][k] = qbf(Wout[k * 32 + c]);
    }
    __syncthreads();

    int gtid = blockIdx.x * 256 + tid;
    int node = gtid >> 6, lane = gtid & 63;
    if (node >= n) return;
    const int beg = offsets[node], end = offsets[node + 1];
    const int wsel = lane & 48;
    const int lo4 = lane * 4;
    float ax = 0.f, ay = 0.f, az = 0.f, aw = 0.f, wsum = 0.f;

#define LDH(T) (*(const ushort4*)&Hb[(size_t)__builtin_amdgcn_readlane(dv, (T)) * 256 + lo4])
#define CONS(B, T) { float w_ = __shfl(wv, wsel + (T));                         \
        ax += w_ * bf2f((B).x); ay += w_ * bf2f((B).y);                         \
        az += w_ * bf2f((B).z); aw += w_ * bf2f((B).w); wsum += w_; }

    for (int j = beg; j < end; j += 16) {
        int slot = j + (lane & 15);
        bool okl = slot < end;
        int dv   = okl ? csrd[slot] : 0;                       // 0 for pad slots
        float wv = okl ? w1[(size_t)slot * 4 + (lane >> 4)] : 0.f;
        int cnt  = min(16, end - j);
        int cntr = (cnt + 3) & ~3;                             // multiple of 4
        ushort4 b0 = LDH(0), b1 = LDH(1), b2 = LDH(2), b3 = LDH(3);
        for (int t0 = 0; t0 < cntr; t0 += 4) {
            ushort4 c0 = b0, c1 = b1, c2 = b2, c3 = b3;
            if (t0 + 4 < cntr) {
                int t4 = t0 + 4;
                c0 = LDH(t4 + 0); c1 = LDH(t4 + 1);
                c2 = LDH(t4 + 2); c3 = LDH(t4 + 3);
            }
            CONS(b0, t0 + 0); CONS(b1, t0 + 1);
            CONS(b2, t0 + 2); CONS(b3, t0 + 3);
            b0 = c0; b1 = c1; b2 = c2; b3 = c3;
        }
    }
#undef LDH
#undef CONS

    float inv = 1.f / wsum;
    float r0 = ax * inv, r1 = ay * inv, r2 = az * inv, r3 = aw * inv;
    r0 = r0 > 0.f ? r0 : expm1f(r0);   // elu -> x1 cols 4L..4L+3
    r1 = r1 > 0.f ? r1 : expm1f(r1);
    r2 = r2 > 0.f ? r2 : expm1f(r2);
    r3 = r3 > 0.f ? r3 : expm1f(r3);

    // fused GEMM2: partial h2[c] over this lane's 4 k's, wave tree-reduce
    float p[32];
#pragma unroll
    for (int c = 0; c < 32; ++c) {
        const float4 wv4 = *(const float4*)&Wt[c][lane << 2];
        p[c] = r0 * wv4.x + r1 * wv4.y + r2 * wv4.z + r3 * wv4.w;
    }
#pragma unroll
    for (int m = 32; m >= 1; m >>= 1) {
#pragma unroll
        for (int c = 0; c < 32; ++c) p[c] += __shfl_xor(p[c], m);
    }
    if (lane == 0) {
        float ss = 0.f, sd2 = 0.f;
#pragma unroll
        for (int c = 0; c < 32; ++c) {
            ss  += p[c] * qbf(aout[c]);
            sd2 += p[c] * qbf(aout[32 + c]);
        }
        float* dst = &h2[(size_t)node * 32];
#pragma unroll
        for (int i = 0; i < 8; ++i)
            *(float4*)&dst[4 * i] = make_float4(p[4 * i + 0], p[4 * i + 1],
                                                p[4 * i + 2], p[4 * i + 3]);
        s2src[node] = ss;
        s2dst[node] = sd2;
    }
}

// ---------------------------------------------------------------------------
// agg2 + elu + log_softmax -> out. One wave per node; dual edge streams
// (lanes 0-31: t = 0,2,..; lanes 32-63: t = 1,3,..), 2-deep pipeline each,
// fold with shfl_xor(32). Divergent-index broadcasts use __shfl (bpermute),
// NOT readlane (readlane needs a uniform index -> r10 bug).
// ---------------------------------------------------------------------------
__global__ __launch_bounds__(256) void k_agg2(const int* __restrict__ csrd,
                                              const int* __restrict__ offsets,
                                              const float* __restrict__ h2,
                                              const float* __restrict__ w2,
                                              float* __restrict__ out, int n)
{
    int gtid = blockIdx.x * 256 + threadIdx.x;
    int node = gtid >> 6, lane = gtid & 63;
    if (node >= n) return;
    int c = lane & 31, p = lane >> 5;
    int beg = offsets[node], end = offsets[node + 1];
    float acc = 0.f, wsum = 0.f;

    for (int j = beg; j < end; j += 64) {
        int slot = j + lane;
        bool okl = slot < end;
        int dv    = okl ? csrd[slot] : 0;
        float wvv = okl ? w2[slot] : 0.f;
        int cnt  = min(64, end - j);
        int cntr = (cnt + 1) & ~1;                 // even
        int t = p;                                  // divergent start per half
        int d0 = __shfl(dv, t);
        float h0 = h2[(size_t)d0 * 32 + c];
        for (; t + 2 < cntr; t += 2) {              // same trip count both halves
            int d1 = __shfl(dv, t + 2);
            float h1 = h2[(size_t)d1 * 32 + c];
            float w = __shfl(wvv, t);
            acc += w * h0; wsum += w;
            h0 = h1;
        }
        float w = __shfl(wvv, t);
        acc += w * h0; wsum += w;
    }

    acc += __shfl_xor(acc, 32);
    wsum += __shfl_xor(wsum, 32);
    float v = acc / wsum;
    v = v > 0.f ? v : expm1f(v);          // elu
    float m = v;
#pragma unroll
    for (int i = 16; i >= 1; i >>= 1) m = fmaxf(m, __shfl_xor(m, i));
    float ex = expf(v - m);
    float se = ex;
#pragma unroll
    for (int i = 16; i >= 1; i >>= 1) se += __shfl_xor(se, i);
    float r = v - m - logf(se);
    if (lane < 32) out[(size_t)node * 32 + c] = r;
}

// ---------------------------------------------------------------------------
extern "C" void kernel_launch(void* const* d_in, const int* in_sizes, int n_in,
                              void* d_out, int out_size, void* d_ws, size_t ws_size,
                              hipStream_t stream)
{
    const float* x    = (const float*)d_in[0];
    const int*   ei   = (const int*)d_in[1];
    const float* Wh   = (const float*)d_in[2];
    const float* ah   = (const float*)d_in[3];
    const float* Wout = (const float*)d_in[4];
    const float* aout = (const float*)d_in[5];
    float* out = (float*)d_out;

    const int n = in_sizes[0] / 256;
    const int e = in_sizes[1] / 2;
    const int* src = ei;
    const int* dst = ei + e;

    auto align = [](size_t v) { return (v + 255) & ~(size_t)255; };
    char* w = (char*)d_ws;
    ushort* Hb    = (ushort*)w; w += align((size_t)n * 256 * 2);  //  51.2 MB (bf16)
    float* h2     = (float*)w; w += align((size_t)n * 32 * 4);    //  12.8 MB
    int*   csr    = (int*)w;   w += align((size_t)e * 4);         //   6.4 MB (edge ids)
    int*   csrd   = (int*)w;   w += align((size_t)e * 4);         //   6.4 MB (dst ids)
    float* w1     = (float*)w; w += align((size_t)e * 4 * 4);     //  25.6 MB
    float* w2     = (float*)w; w += align((size_t)e * 4);         //   6.4 MB
    float* s1src  = (float*)w; w += align((size_t)n * 4 * 4);
    float* s1dst  = (float*)w; w += align((size_t)n * 4 * 4);
    int*   counts = (int*)w;   w += align((size_t)n * 4);
    int*   offs   = (int*)w;   w += align((size_t)(n + 1) * 4);
    int*   cursor = (int*)w;   w += align((size_t)n * 4);
    float* s2src  = (float*)w; w += align((size_t)n * 4);
    float* s2dst  = (float*)w; w += align((size_t)n * 4);
    int*   bsum   = (int*)w;   w += align(4096);
    int*   choff  = (int*)w;   w += align(4096);

    const int nchunk = (n + 2047) / 2048;
    const int gN256  = (n + 255) / 256;
    const int gWave  = (n + 3) / 4;      // 4 node-waves per 256-thread block
    const int gE     = (e + 255) / 256;

    // layer 1 feature transform (+ fused attention scores), bf16 H out
    k_gemm1<<<(n + 63) / 64, 256, 0, stream>>>(x, Wh, ah, Hb, s1src, s1dst, n);

    // deterministic CSR by src (sorted edge-id buckets)
    k_zero<<<gN256, 256, 0, stream>>>(counts, n);
    k_hist<<<gE, 256, 0, stream>>>(src, counts, e);
    k_blocksum<<<nchunk, 256, 0, stream>>>(counts, bsum, n);
    k_scanmeta<<<1, 64, 0, stream>>>(bsum, choff, nchunk);
    k_apply<<<nchunk, 256, 0, stream>>>(counts, choff, offs, cursor, n);
    k_scatter<<<gE, 256, 0, stream>>>(src, cursor, csr, e);
    k_sortcsr<<<gWave, 256, 0, stream>>>(offs, csr, n);

    // edge weights layer 1 (+ dst ids in csr order)
    k_w1<<<gE, 256, 0, stream>>>(csr, src, dst, s1src, s1dst, csrd, w1, e);

    // layer 1 aggregation + fused layer-2 transform
    k_agg1<<<gWave, 256, 0, stream>>>(csrd, offs, Hb, w1, Wout, aout,
                                      h2, s2src, s2dst, n);
    // edge weights layer 2
    k_w2<<<gE, 256, 0, stream>>>(csr, src, dst, s2src, s2dst, w2, e);

    // layer 2 aggregation + elu + log_softmax
    k_agg2<<<gWave, 256, 0, stream>>>(csrd, offs, h2, w2, out, n);
}